// Round 2
// baseline (498.428 us; speedup 1.0000x reference)
//
#include <hip/hip_runtime.h>

#define NEG_SLOPE 0.2f

// -------- GEMM: h[N,64] = x[N,128] @ W[128,64], fp32 --------
// W (32 KB) staged in LDS; each thread computes one full output row.
// LDS reads of W rows are wave-uniform -> broadcast, conflict-free.
__global__ __launch_bounds__(256) void gemm_xw(const float* __restrict__ x,
                                               const float* __restrict__ W,
                                               float* __restrict__ h, int N) {
  __shared__ float Wl[128 * 64];
  {
    const float4* Wv = (const float4*)W;
    float4* Wlv = (float4*)Wl;
    for (int i = threadIdx.x; i < 128 * 16; i += 256) Wlv[i] = Wv[i];
  }
  __syncthreads();
  int r = blockIdx.x * 256 + threadIdx.x;
  if (r >= N) return;
  float4 acc[16];
#pragma unroll
  for (int i = 0; i < 16; i++) acc[i] = make_float4(0.f, 0.f, 0.f, 0.f);
  const float4* xr = (const float4*)(x + (size_t)r * 128);
#pragma unroll 2
  for (int kq = 0; kq < 32; kq++) {
    float4 xv = xr[kq];
#pragma unroll
    for (int kk = 0; kk < 4; kk++) {
      float xs = (kk == 0) ? xv.x : (kk == 1) ? xv.y : (kk == 2) ? xv.z : xv.w;
      const float4* wrow = (const float4*)(&Wl[(kq * 4 + kk) * 64]);
#pragma unroll
      for (int c4 = 0; c4 < 16; c4++) {
        float4 wv = wrow[c4];
        acc[c4].x = fmaf(xs, wv.x, acc[c4].x);
        acc[c4].y = fmaf(xs, wv.y, acc[c4].y);
        acc[c4].z = fmaf(xs, wv.z, acc[c4].z);
        acc[c4].w = fmaf(xs, wv.w, acc[c4].w);
      }
    }
  }
  float4* ho = (float4*)(h + (size_t)r * 64);
#pragma unroll
  for (int c4 = 0; c4 < 16; c4++) ho[c4] = acc[c4];
}

// -------- Edge pass: one wave per edge (grid-stride) --------
// lane c (0..63) owns channel c of head c>>4.
// alpha = sum_c leakyrelu(h_i+h_j)*att  (4-step shfl_xor reduce per 16-lane head)
// p = exp(alpha)   [max-shift dropped: ratio p/denom is shift-invariant]
// atomicAdd out[row,c] += p * h_j[c];  atomicAdd denom[row,h] += p
__global__ __launch_bounds__(256) void edge_pass(const float* __restrict__ h,
                                                 const int* __restrict__ rowi,
                                                 const int* __restrict__ coli,
                                                 const float* __restrict__ att,
                                                 float* __restrict__ outacc,
                                                 float* __restrict__ denom,
                                                 int E, int N) {
  const int lane = threadIdx.x & 63;
  const int wid = (blockIdx.x * blockDim.x + threadIdx.x) >> 6;
  const int nw = (gridDim.x * blockDim.x) >> 6;
  const int Etot = E + N;
  const float attv = att[lane];  // att[h*16+c] with lane = h*16+c
  for (int e = wid; e < Etot; e += nw) {
    int r, c;
    if (e < E) {
      r = rowi[e];
      c = coli[e];
    } else {
      r = c = e - E;  // self loop
    }
    float hj = h[(c << 6) | lane];
    float hi = h[(r << 6) | lane];
    float s = hi + hj;
    float a = (s > 0.f ? s : NEG_SLOPE * s) * attv;
    a += __shfl_xor(a, 1);
    a += __shfl_xor(a, 2);
    a += __shfl_xor(a, 4);
    a += __shfl_xor(a, 8);
    float p = __expf(a);
    atomicAdd(&outacc[(r << 6) | lane], p * hj);
    if ((lane & 15) == 0) atomicAdd(&denom[(r << 2) | (lane >> 4)], p);
  }
}

// -------- Normalize + bias: out = out/(denom+eps) + bias --------
__global__ __launch_bounds__(256) void norm_bias(float4* __restrict__ out,
                                                 const float* __restrict__ denom,
                                                 const float* __restrict__ bias,
                                                 int N) {
  int i = blockIdx.x * 256 + threadIdx.x;
  if (i >= N * 16) return;
  int n = i >> 4;
  int c4 = i & 15;
  float d = denom[(n << 2) | (c4 >> 2)] + 1e-16f;
  float inv = 1.0f / d;
  const float4 b = ((const float4*)bias)[c4];
  float4 v = out[i];
  v.x = fmaf(v.x, inv, b.x);
  v.y = fmaf(v.y, inv, b.y);
  v.z = fmaf(v.z, inv, b.z);
  v.w = fmaf(v.w, inv, b.w);
  out[i] = v;
}

extern "C" void kernel_launch(void* const* d_in, const int* in_sizes, int n_in,
                              void* d_out, int out_size, void* d_ws, size_t ws_size,
                              hipStream_t stream) {
  const float* x = (const float*)d_in[0];
  const int* eidx = (const int*)d_in[1];  // int32 per harness conversion
  const float* W = (const float*)d_in[2];
  const float* att = (const float*)d_in[3];
  const float* bias = (const float*)d_in[4];
  float* out = (float*)d_out;

  const int N = in_sizes[0] / 128;
  const int E = in_sizes[1] / 2;

  float* h = (float*)d_ws;                  // N*64 floats = 25.6 MB
  float* denom = h + (size_t)N * 64;        // N*4 floats  =  1.6 MB

  hipMemsetAsync(d_out, 0, (size_t)out_size * sizeof(float), stream);
  hipMemsetAsync(denom, 0, (size_t)N * 4 * sizeof(float), stream);

  gemm_xw<<<(N + 255) / 256, 256, 0, stream>>>(x, W, h, N);
  edge_pass<<<2048, 256, 0, stream>>>(h, eidx, eidx + E, att, out, denom, E, N);

  int tot4 = N * 16;
  norm_bias<<<(tot4 + 255) / 256, 256, 0, stream>>>((float4*)out, denom, bias, N);
}

// Round 3
// 373.637 us; speedup vs baseline: 1.3340x; 1.3340x over previous
//
#include <hip/hip_runtime.h>

#define NEG_SLOPE 0.2f

// ---- bf16 helpers (raw-bit, RNE) ----
__device__ __forceinline__ unsigned short f2bf(float f) {
  union { float f; unsigned u; } v; v.f = f;
  unsigned r = v.u + 0x7fff + ((v.u >> 16) & 1);
  return (unsigned short)(r >> 16);
}
__device__ __forceinline__ float bf2f(unsigned short u) {
  union { unsigned u; float f; } v; v.u = ((unsigned)u) << 16;
  return v.f;
}

// -------- GEMM: hb[N,64](bf16) = x[N,128] @ W[128,64] --------
__global__ __launch_bounds__(256) void gemm_xw(const float* __restrict__ x,
                                               const float* __restrict__ W,
                                               unsigned short* __restrict__ hb, int N) {
  __shared__ float Wl[128 * 64];
  {
    const float4* Wv = (const float4*)W;
    float4* Wlv = (float4*)Wl;
    for (int i = threadIdx.x; i < 128 * 16; i += 256) Wlv[i] = Wv[i];
  }
  __syncthreads();
  int r = blockIdx.x * 256 + threadIdx.x;
  if (r >= N) return;
  float4 acc[16];
#pragma unroll
  for (int i = 0; i < 16; i++) acc[i] = make_float4(0.f, 0.f, 0.f, 0.f);
  const float4* xr = (const float4*)(x + (size_t)r * 128);
#pragma unroll 2
  for (int kq = 0; kq < 32; kq++) {
    float4 xv = xr[kq];
#pragma unroll
    for (int kk = 0; kk < 4; kk++) {
      float xs = (kk == 0) ? xv.x : (kk == 1) ? xv.y : (kk == 2) ? xv.z : xv.w;
      const float4* wrow = (const float4*)(&Wl[(kq * 4 + kk) * 64]);
#pragma unroll
      for (int c4 = 0; c4 < 16; c4++) {
        float4 wv = wrow[c4];
        acc[c4].x = fmaf(xs, wv.x, acc[c4].x);
        acc[c4].y = fmaf(xs, wv.y, acc[c4].y);
        acc[c4].z = fmaf(xs, wv.z, acc[c4].z);
        acc[c4].w = fmaf(xs, wv.w, acc[c4].w);
      }
    }
  }
  uint2* hv = (uint2*)(hb + (size_t)r * 64);
#pragma unroll
  for (int c4 = 0; c4 < 16; c4++) {
    unsigned p01 = (unsigned)f2bf(acc[c4].x) | ((unsigned)f2bf(acc[c4].y) << 16);
    unsigned p23 = (unsigned)f2bf(acc[c4].z) | ((unsigned)f2bf(acc[c4].w) << 16);
    hv[c4] = make_uint2(p01, p23);
  }
}

// -------- CSR build: histogram -> scan -> scatter --------
__global__ __launch_bounds__(256) void hist_rows(const int* __restrict__ rowi,
                                                 int* __restrict__ cnt, int E) {
  int i = blockIdx.x * blockDim.x + threadIdx.x;
  int stride = gridDim.x * blockDim.x;
  for (; i < E; i += stride) atomicAdd(&cnt[rowi[i]], 1);
}

#define SCAN_T 256
#define SCAN_I 8
#define SCAN_CHUNK 2048

__global__ __launch_bounds__(SCAN_T) void scan_reduce(const int* __restrict__ cnt,
                                                      int* __restrict__ bsum, int N) {
  __shared__ int sd[SCAN_T];
  int base = blockIdx.x * SCAN_CHUNK;
  int s = 0;
  for (int i = threadIdx.x; i < SCAN_CHUNK; i += SCAN_T) {
    int idx = base + i;
    s += (idx < N) ? cnt[idx] : 0;
  }
  sd[threadIdx.x] = s;
  __syncthreads();
  for (int off = 128; off > 0; off >>= 1) {
    if (threadIdx.x < off) sd[threadIdx.x] += sd[threadIdx.x + off];
    __syncthreads();
  }
  if (threadIdx.x == 0) bsum[blockIdx.x] = sd[0];
}

__global__ __launch_bounds__(SCAN_T) void scan_bsums(int* __restrict__ bsum, int NB) {
  __shared__ int a[SCAN_T], b[SCAN_T];
  int t = threadIdx.x;
  int v = (t < NB) ? bsum[t] : 0;
  a[t] = v;
  __syncthreads();
  int* src = a;
  int* dst = b;
  for (int off = 1; off < SCAN_T; off <<= 1) {
    int val = src[t] + ((t >= off) ? src[t - off] : 0);
    dst[t] = val;
    __syncthreads();
    int* tmp = src; src = dst; dst = tmp;
  }
  if (t < NB) bsum[t] = src[t] - v;  // exclusive
}

__global__ __launch_bounds__(SCAN_T) void scan_final(const int* __restrict__ cnt,
                                                     const int* __restrict__ bsum,
                                                     int* __restrict__ offs,
                                                     int* __restrict__ cursor, int N) {
  __shared__ int a[SCAN_T], b[SCAN_T];
  int t = threadIdx.x;
  int base = blockIdx.x * SCAN_CHUNK;
  int mybase = base + t * SCAN_I;
  int loc[SCAN_I];
  int s = 0;
#pragma unroll
  for (int i = 0; i < SCAN_I; i++) {
    int idx = mybase + i;
    int v = (idx < N) ? cnt[idx] : 0;
    loc[i] = s;
    s += v;
  }
  a[t] = s;
  __syncthreads();
  int* src = a;
  int* dst = b;
  for (int off = 1; off < SCAN_T; off <<= 1) {
    int val = src[t] + ((t >= off) ? src[t - off] : 0);
    dst[t] = val;
    __syncthreads();
    int* tmp = src; src = dst; dst = tmp;
  }
  int texcl = src[t] - s;
  int boff = bsum[blockIdx.x];
#pragma unroll
  for (int i = 0; i < SCAN_I; i++) {
    int idx = mybase + i;
    if (idx < N) {
      int o = boff + texcl + loc[i];
      offs[idx] = o;
      cursor[idx] = o;
    }
  }
}

__global__ __launch_bounds__(256) void scatter_edges(const int* __restrict__ rowi,
                                                     const int* __restrict__ coli,
                                                     int* __restrict__ cursor,
                                                     int* __restrict__ srcs, int E) {
  int i = blockIdx.x * blockDim.x + threadIdx.x;
  int stride = gridDim.x * blockDim.x;
  for (; i < E; i += stride) {
    int r = rowi[i];
    int pos = atomicAdd(&cursor[r], 1);
    srcs[pos] = coli[i];
  }
}

// -------- Node pass: one wave per destination node --------
// lane = channel (head = lane>>4). Accumulate out/denom in registers,
// write the output row exactly once. Softmax max-shift dropped (shift-
// invariant); normalization applied in the epilogue.
__global__ __launch_bounds__(256) void node_pass(const unsigned short* __restrict__ hb,
                                                 const int* __restrict__ offs,
                                                 const int* __restrict__ rowend,
                                                 const int* __restrict__ srcs,
                                                 const float* __restrict__ att,
                                                 const float* __restrict__ bias,
                                                 float* __restrict__ out, int N) {
  int w = (blockIdx.x * blockDim.x + threadIdx.x) >> 6;
  if (w >= N) return;
  const int lane = threadIdx.x & 63;
  const float attv = att[lane];
  const float hi = bf2f(hb[(size_t)w * 64 + lane]);
  // self loop
  float s0 = hi + hi;
  float a0 = (s0 > 0.f ? s0 : NEG_SLOPE * s0) * attv;
  a0 += __shfl_xor(a0, 1);
  a0 += __shfl_xor(a0, 2);
  a0 += __shfl_xor(a0, 4);
  a0 += __shfl_xor(a0, 8);
  float p0 = __expf(a0);
  float acc = p0 * hi;
  float den = p0;
  int k = offs[w];
  const int k1 = rowend[w];
  for (; k + 1 < k1; k += 2) {
    int c0 = srcs[k];
    int c1 = srcs[k + 1];
    float hj0 = bf2f(hb[(size_t)c0 * 64 + lane]);
    float hj1 = bf2f(hb[(size_t)c1 * 64 + lane]);
    float sa = hi + hj0, sb = hi + hj1;
    float aa = (sa > 0.f ? sa : NEG_SLOPE * sa) * attv;
    float ab = (sb > 0.f ? sb : NEG_SLOPE * sb) * attv;
    aa += __shfl_xor(aa, 1); ab += __shfl_xor(ab, 1);
    aa += __shfl_xor(aa, 2); ab += __shfl_xor(ab, 2);
    aa += __shfl_xor(aa, 4); ab += __shfl_xor(ab, 4);
    aa += __shfl_xor(aa, 8); ab += __shfl_xor(ab, 8);
    float pa = __expf(aa);
    float pb = __expf(ab);
    acc = fmaf(pa, hj0, acc);
    acc = fmaf(pb, hj1, acc);
    den += pa + pb;
  }
  if (k < k1) {
    int c0 = srcs[k];
    float hj0 = bf2f(hb[(size_t)c0 * 64 + lane]);
    float sa = hi + hj0;
    float aa = (sa > 0.f ? sa : NEG_SLOPE * sa) * attv;
    aa += __shfl_xor(aa, 1);
    aa += __shfl_xor(aa, 2);
    aa += __shfl_xor(aa, 4);
    aa += __shfl_xor(aa, 8);
    float pa = __expf(aa);
    acc = fmaf(pa, hj0, acc);
    den += pa;
  }
  out[(size_t)w * 64 + lane] = acc / (den + 1e-16f) + bias[lane];
}

extern "C" void kernel_launch(void* const* d_in, const int* in_sizes, int n_in,
                              void* d_out, int out_size, void* d_ws, size_t ws_size,
                              hipStream_t stream) {
  const float* x = (const float*)d_in[0];
  const int* eidx = (const int*)d_in[1];  // int32 per harness conversion
  const float* W = (const float*)d_in[2];
  const float* att = (const float*)d_in[3];
  const float* bias = (const float*)d_in[4];
  float* out = (float*)d_out;

  const int N = in_sizes[0] / 128;
  const int E = in_sizes[1] / 2;
  const int NB = (N + SCAN_CHUNK - 1) / SCAN_CHUNK;

  unsigned short* hb = (unsigned short*)d_ws;      // N*64*2 = 12.8 MB
  int* cnt = (int*)(hb + (size_t)N * 64);          // N*4
  int* offs = cnt + N;                             // N*4
  int* cursor = offs + N;                          // N*4
  int* srcs = cursor + N;                          // E*4
  int* bsum = srcs + E;                            // NB*4

  hipMemsetAsync(cnt, 0, (size_t)N * sizeof(int), stream);

  gemm_xw<<<(N + 255) / 256, 256, 0, stream>>>(x, W, hb, N);
  hist_rows<<<2048, 256, 0, stream>>>(eidx, cnt, E);
  scan_reduce<<<NB, SCAN_T, 0, stream>>>(cnt, bsum, N);
  scan_bsums<<<1, SCAN_T, 0, stream>>>(bsum, NB);
  scan_final<<<NB, SCAN_T, 0, stream>>>(cnt, bsum, offs, cursor, N);
  scatter_edges<<<2048, 256, 0, stream>>>(eidx, eidx + E, cursor, srcs, E);
  node_pass<<<(N * 64 + 255) / 256, 256, 0, stream>>>(hb, offs, cursor, srcs, att, bias,
                                                      out, N);
}

// Round 4
// 277.492 us; speedup vs baseline: 1.7962x; 1.3465x over previous
//
#include <hip/hip_runtime.h>

#define NEG_SLOPE 0.2f

// ---- bf16 helpers (raw-bit, RNE) ----
__device__ __forceinline__ unsigned short f2bf(float f) {
  union { float f; unsigned u; } v; v.f = f;
  unsigned r = v.u + 0x7fff + ((v.u >> 16) & 1);
  return (unsigned short)(r >> 16);
}
__device__ __forceinline__ float bf2f(unsigned short u) {
  union { unsigned u; float f; } v; v.u = ((unsigned)u) << 16;
  return v.f;
}

// -------- GEMM: hb[N,64](bf16) = x[N,128] @ W[128,64] --------
__global__ __launch_bounds__(256) void gemm_xw(const float* __restrict__ x,
                                               const float* __restrict__ W,
                                               unsigned short* __restrict__ hb, int N) {
  __shared__ float Wl[128 * 64];
  {
    const float4* Wv = (const float4*)W;
    float4* Wlv = (float4*)Wl;
    for (int i = threadIdx.x; i < 128 * 16; i += 256) Wlv[i] = Wv[i];
  }
  __syncthreads();
  int r = blockIdx.x * 256 + threadIdx.x;
  if (r >= N) return;
  float4 acc[16];
#pragma unroll
  for (int i = 0; i < 16; i++) acc[i] = make_float4(0.f, 0.f, 0.f, 0.f);
  const float4* xr = (const float4*)(x + (size_t)r * 128);
#pragma unroll 2
  for (int kq = 0; kq < 32; kq++) {
    float4 xv = xr[kq];
#pragma unroll
    for (int kk = 0; kk < 4; kk++) {
      float xs = (kk == 0) ? xv.x : (kk == 1) ? xv.y : (kk == 2) ? xv.z : xv.w;
      const float4* wrow = (const float4*)(&Wl[(kq * 4 + kk) * 64]);
#pragma unroll
      for (int c4 = 0; c4 < 16; c4++) {
        float4 wv = wrow[c4];
        acc[c4].x = fmaf(xs, wv.x, acc[c4].x);
        acc[c4].y = fmaf(xs, wv.y, acc[c4].y);
        acc[c4].z = fmaf(xs, wv.z, acc[c4].z);
        acc[c4].w = fmaf(xs, wv.w, acc[c4].w);
      }
    }
  }
  uint2* hv = (uint2*)(hb + (size_t)r * 64);
#pragma unroll
  for (int c4 = 0; c4 < 16; c4++) {
    unsigned p01 = (unsigned)f2bf(acc[c4].x) | ((unsigned)f2bf(acc[c4].y) << 16);
    unsigned p23 = (unsigned)f2bf(acc[c4].z) | ((unsigned)f2bf(acc[c4].w) << 16);
    hv[c4] = make_uint2(p01, p23);
  }
}

// -------- CSR build --------
__global__ __launch_bounds__(256) void hist_rows(const int* __restrict__ rowi,
                                                 int* __restrict__ cnt, int E) {
  int i = blockIdx.x * blockDim.x + threadIdx.x;
  int stride = gridDim.x * blockDim.x;
  for (; i < E; i += stride) atomicAdd(&cnt[rowi[i]], 1);
}

#define SCAN_T 256
#define SCAN_I 8
#define SCAN_CHUNK 2048

__global__ __launch_bounds__(SCAN_T) void scan_reduce(const int* __restrict__ cnt,
                                                      int* __restrict__ bsum, int N) {
  __shared__ int sd[SCAN_T];
  int base = blockIdx.x * SCAN_CHUNK;
  int s = 0;
  for (int i = threadIdx.x; i < SCAN_CHUNK; i += SCAN_T) {
    int idx = base + i;
    s += (idx < N) ? cnt[idx] : 0;
  }
  sd[threadIdx.x] = s;
  __syncthreads();
  for (int off = 128; off > 0; off >>= 1) {
    if (threadIdx.x < off) sd[threadIdx.x] += sd[threadIdx.x + off];
    __syncthreads();
  }
  if (threadIdx.x == 0) bsum[blockIdx.x] = sd[0];
}

__global__ __launch_bounds__(SCAN_T) void scan_bsums(int* __restrict__ bsum, int NB) {
  __shared__ int a[SCAN_T], b[SCAN_T];
  int t = threadIdx.x;
  int v = (t < NB) ? bsum[t] : 0;
  a[t] = v;
  __syncthreads();
  int* src = a;
  int* dst = b;
  for (int off = 1; off < SCAN_T; off <<= 1) {
    int val = src[t] + ((t >= off) ? src[t - off] : 0);
    dst[t] = val;
    __syncthreads();
    int* tmp = src; src = dst; dst = tmp;
  }
  if (t < NB) bsum[t] = src[t] - v;  // exclusive
}

__global__ __launch_bounds__(SCAN_T) void scan_final(const int* __restrict__ cnt,
                                                     const int* __restrict__ bsum,
                                                     int* __restrict__ offs,
                                                     int* __restrict__ cursor, int N) {
  __shared__ int a[SCAN_T], b[SCAN_T];
  int t = threadIdx.x;
  int base = blockIdx.x * SCAN_CHUNK;
  int mybase = base + t * SCAN_I;
  int loc[SCAN_I];
  int s = 0;
#pragma unroll
  for (int i = 0; i < SCAN_I; i++) {
    int idx = mybase + i;
    int v = (idx < N) ? cnt[idx] : 0;
    loc[i] = s;
    s += v;
  }
  a[t] = s;
  __syncthreads();
  int* src = a;
  int* dst = b;
  for (int off = 1; off < SCAN_T; off <<= 1) {
    int val = src[t] + ((t >= off) ? src[t - off] : 0);
    dst[t] = val;
    __syncthreads();
    int* tmp = src; src = dst; dst = tmp;
  }
  int texcl = src[t] - s;
  int boff = bsum[blockIdx.x];
#pragma unroll
  for (int i = 0; i < SCAN_I; i++) {
    int idx = mybase + i;
    if (idx < N) {
      int o = boff + texcl + loc[i];
      offs[idx] = o;
      cursor[idx] = o;
    }
  }
}

// Partitioned scatter: group g = blockIdx&7 handles row range g (default
// block->XCD mapping is round-robin, so each srcs line is written by one
// XCD only -> lines stay in that L2 and write back once).
__global__ __launch_bounds__(256) void scatter_part(const int* __restrict__ rowi,
                                                    const int* __restrict__ coli,
                                                    int* __restrict__ cursor,
                                                    int* __restrict__ srcs, int E, int N) {
  int g = blockIdx.x & 7;
  int lo = (int)(((long long)g * N) >> 3);
  int hi = (int)(((long long)(g + 1) * N) >> 3);
  int stride = (gridDim.x >> 3) * blockDim.x;
  for (int i = (blockIdx.x >> 3) * blockDim.x + threadIdx.x; i < E; i += stride) {
    int r = rowi[i];
    if (r >= lo && r < hi) {
      int pos = atomicAdd(&cursor[r], 1);
      srcs[pos] = coli[i];
    }
  }
}

// -------- Node pass: one wave per node, 2 channels/lane, 2 edges/wave --------
// lane lr=lane&31 owns channels {2lr,2lr+1}; half-wave (lane>>5) owns edge
// stream A/B. Head h = lr>>3 -> reduce via shfl_xor 1,2,4 within 8 lanes.
// Softmax max-shift dropped (shift-invariant); normalize in epilogue.
__global__ __launch_bounds__(256) void node_pass(const unsigned short* __restrict__ hb,
                                                 const int* __restrict__ offs,
                                                 const int* __restrict__ rowend,
                                                 const int* __restrict__ srcs,
                                                 const float* __restrict__ att,
                                                 const float* __restrict__ bias,
                                                 float* __restrict__ out, int N) {
  int w = (blockIdx.x * blockDim.x + threadIdx.x) >> 6;
  if (w >= N) return;
  const int lane = threadIdx.x & 63;
  const int lr = lane & 31;
  const int half = lane >> 5;
  const float2 attv = *(const float2*)(att + 2 * lr);
  unsigned ui = *(const unsigned*)(hb + (size_t)w * 64 + 2 * lr);
  const float hi0 = bf2f((unsigned short)(ui & 0xffffu));
  const float hi1 = bf2f((unsigned short)(ui >> 16));
  float acc0, acc1, den;
  {  // self loop (half A only contributes)
    float s0 = hi0 + hi0, s1 = hi1 + hi1;
    float a = (s0 > 0.f ? s0 : NEG_SLOPE * s0) * attv.x +
              (s1 > 0.f ? s1 : NEG_SLOPE * s1) * attv.y;
    a += __shfl_xor(a, 1);
    a += __shfl_xor(a, 2);
    a += __shfl_xor(a, 4);
    float p = half ? 0.f : __expf(a);
    acc0 = p * hi0;
    acc1 = p * hi1;
    den = p;
  }
  int k = offs[w];
  const int k1 = rowend[w];
  // main: 4 edges per iteration (2 per half-wave)
  for (; k + 4 <= k1; k += 4) {
    int ca = srcs[k + half];
    int cb = srcs[k + 2 + half];
    unsigned ua = *(const unsigned*)(hb + (size_t)ca * 64 + 2 * lr);
    unsigned ub = *(const unsigned*)(hb + (size_t)cb * 64 + 2 * lr);
    float a0 = bf2f((unsigned short)(ua & 0xffffu)), a1 = bf2f((unsigned short)(ua >> 16));
    float b0 = bf2f((unsigned short)(ub & 0xffffu)), b1 = bf2f((unsigned short)(ub >> 16));
    float sa0 = hi0 + a0, sa1 = hi1 + a1, sb0 = hi0 + b0, sb1 = hi1 + b1;
    float aa = (sa0 > 0.f ? sa0 : NEG_SLOPE * sa0) * attv.x +
               (sa1 > 0.f ? sa1 : NEG_SLOPE * sa1) * attv.y;
    float ab = (sb0 > 0.f ? sb0 : NEG_SLOPE * sb0) * attv.x +
               (sb1 > 0.f ? sb1 : NEG_SLOPE * sb1) * attv.y;
    aa += __shfl_xor(aa, 1); ab += __shfl_xor(ab, 1);
    aa += __shfl_xor(aa, 2); ab += __shfl_xor(ab, 2);
    aa += __shfl_xor(aa, 4); ab += __shfl_xor(ab, 4);
    float pa = __expf(aa);
    float pb = __expf(ab);
    acc0 = fmaf(pa, a0, acc0); acc1 = fmaf(pa, a1, acc1);
    acc0 = fmaf(pb, b0, acc0); acc1 = fmaf(pb, b1, acc1);
    den += pa + pb;
  }
  // tail: 0-3 edges
  for (; k < k1; k += 2) {
    int kk = k + half;
    bool act = kk < k1;
    int c = act ? srcs[kk] : w;
    unsigned u = *(const unsigned*)(hb + (size_t)c * 64 + 2 * lr);
    float j0 = bf2f((unsigned short)(u & 0xffffu)), j1 = bf2f((unsigned short)(u >> 16));
    float s0 = hi0 + j0, s1 = hi1 + j1;
    float a = (s0 > 0.f ? s0 : NEG_SLOPE * s0) * attv.x +
              (s1 > 0.f ? s1 : NEG_SLOPE * s1) * attv.y;
    a += __shfl_xor(a, 1);
    a += __shfl_xor(a, 2);
    a += __shfl_xor(a, 4);
    float p = act ? __expf(a) : 0.f;
    acc0 = fmaf(p, j0, acc0);
    acc1 = fmaf(p, j1, acc1);
    den += p;
  }
  // combine halves
  acc0 += __shfl_xor(acc0, 32);
  acc1 += __shfl_xor(acc1, 32);
  den += __shfl_xor(den, 32);
  if (!half) {
    float inv = 1.0f / (den + 1e-16f);
    const float2 b = *(const float2*)(bias + 2 * lr);
    float2 o;
    o.x = fmaf(acc0, inv, b.x);
    o.y = fmaf(acc1, inv, b.y);
    *(float2*)(out + (size_t)w * 64 + 2 * lr) = o;
  }
}

extern "C" void kernel_launch(void* const* d_in, const int* in_sizes, int n_in,
                              void* d_out, int out_size, void* d_ws, size_t ws_size,
                              hipStream_t stream) {
  const float* x = (const float*)d_in[0];
  const int* eidx = (const int*)d_in[1];  // int32 per harness conversion
  const float* W = (const float*)d_in[2];
  const float* att = (const float*)d_in[3];
  const float* bias = (const float*)d_in[4];
  float* out = (float*)d_out;

  const int N = in_sizes[0] / 128;
  const int E = in_sizes[1] / 2;
  const int NB = (N + SCAN_CHUNK - 1) / SCAN_CHUNK;

  unsigned short* hb = (unsigned short*)d_ws;      // N*64*2 = 12.8 MB
  int* cnt = (int*)(hb + (size_t)N * 64);          // N*4
  int* offs = cnt + N;                             // N*4
  int* cursor = offs + N;                          // N*4
  int* srcs = cursor + N;                          // E*4
  int* bsum = srcs + E;                            // NB*4

  hipMemsetAsync(cnt, 0, (size_t)N * sizeof(int), stream);

  gemm_xw<<<(N + 255) / 256, 256, 0, stream>>>(x, W, hb, N);
  hist_rows<<<2048, 256, 0, stream>>>(eidx, cnt, E);
  scan_reduce<<<NB, SCAN_T, 0, stream>>>(cnt, bsum, N);
  scan_bsums<<<1, SCAN_T, 0, stream>>>(bsum, NB);
  scan_final<<<NB, SCAN_T, 0, stream>>>(cnt, bsum, offs, cursor, N);
  scatter_part<<<2048, 256, 0, stream>>>(eidx, eidx + E, cursor, srcs, E, N);
  node_pass<<<(N * 64 + 255) / 256, 256, 0, stream>>>(hb, offs, cursor, srcs, att, bias,
                                                      out, N);
}

// Round 5
// 257.573 us; speedup vs baseline: 1.9351x; 1.0773x over previous
//
#include <hip/hip_runtime.h>

#define NEG_SLOPE 0.2f

typedef float f32x2 __attribute__((ext_vector_type(2)));

// ---- bf16 helpers (raw-bit, RNE) ----
__device__ __forceinline__ unsigned short f2bf(float f) {
  union { float f; unsigned u; } v; v.f = f;
  unsigned r = v.u + 0x7fff + ((v.u >> 16) & 1);
  return (unsigned short)(r >> 16);
}
__device__ __forceinline__ unsigned pkbf(float a, float b) {
  return (unsigned)f2bf(a) | ((unsigned)f2bf(b) << 16);
}
__device__ __forceinline__ f32x2 upk(unsigned u) {
  union { unsigned u; float f; } lo, hi;
  lo.u = u << 16;
  hi.u = u & 0xffff0000u;
  f32x2 r;
  r.x = lo.f;
  r.y = hi.f;
  return r;
}

// -------- GEMM: hb[N,64](bf16) = x[N,128] @ W[128,64] --------
// 4 threads per row, 16 cols each -> 400K threads (6 waves/SIMD).
// LDS W reads: 4 distinct addresses/wave, 2-way bank alias (free).
__global__ __launch_bounds__(256) void gemm_xw(const float* __restrict__ x,
                                               const float* __restrict__ W,
                                               unsigned short* __restrict__ hb, int N) {
  __shared__ float Wl[128 * 64];
  {
    const float4* Wv = (const float4*)W;
    float4* Wlv = (float4*)Wl;
    for (int i = threadIdx.x; i < 128 * 16; i += 256) Wlv[i] = Wv[i];
  }
  __syncthreads();
  int t = blockIdx.x * 256 + threadIdx.x;
  int r = t >> 2;
  if (r >= N) return;
  const int cg = (t & 3) * 16;  // column group [cg, cg+16)
  float4 acc[4];
#pragma unroll
  for (int i = 0; i < 4; i++) acc[i] = make_float4(0.f, 0.f, 0.f, 0.f);
  const float4* xr = (const float4*)(x + (size_t)r * 128);
#pragma unroll 4
  for (int kq = 0; kq < 32; kq++) {
    float4 xv = xr[kq];
#pragma unroll
    for (int kk = 0; kk < 4; kk++) {
      float xs = (kk == 0) ? xv.x : (kk == 1) ? xv.y : (kk == 2) ? xv.z : xv.w;
      const float4* wrow = (const float4*)(&Wl[(kq * 4 + kk) * 64 + cg]);
#pragma unroll
      for (int c4 = 0; c4 < 4; c4++) {
        float4 wv = wrow[c4];
        acc[c4].x = fmaf(xs, wv.x, acc[c4].x);
        acc[c4].y = fmaf(xs, wv.y, acc[c4].y);
        acc[c4].z = fmaf(xs, wv.z, acc[c4].z);
        acc[c4].w = fmaf(xs, wv.w, acc[c4].w);
      }
    }
  }
  unsigned short* hp = hb + (size_t)r * 64 + cg;
  uint4 o0, o1;
  o0.x = pkbf(acc[0].x, acc[0].y); o0.y = pkbf(acc[0].z, acc[0].w);
  o0.z = pkbf(acc[1].x, acc[1].y); o0.w = pkbf(acc[1].z, acc[1].w);
  o1.x = pkbf(acc[2].x, acc[2].y); o1.y = pkbf(acc[2].z, acc[2].w);
  o1.z = pkbf(acc[3].x, acc[3].y); o1.w = pkbf(acc[3].z, acc[3].w);
  *(uint4*)hp = o0;
  *(uint4*)(hp + 8) = o1;
}

// -------- CSR build --------
// Partitioned histogram: group g handles rows [gN/8,(g+1)N/8) -> cnt atomics
// stay in one XCD's L2 (blockIdx&7 ~ round-robin XCD mapping; perf-only).
__global__ __launch_bounds__(256) void hist_rows(const int* __restrict__ rowi,
                                                 int* __restrict__ cnt, int E, int N) {
  int g = blockIdx.x & 7;
  int lo = (int)(((long long)g * N) >> 3);
  int hi = (int)(((long long)(g + 1) * N) >> 3);
  int stride = (gridDim.x >> 3) * blockDim.x;
  for (int i = (blockIdx.x >> 3) * blockDim.x + threadIdx.x; i < E; i += stride) {
    int r = rowi[i];
    if (r >= lo && r < hi) atomicAdd(&cnt[r], 1);
  }
}

#define SCAN_T 256
#define SCAN_I 8
#define SCAN_CHUNK 2048

__global__ __launch_bounds__(SCAN_T) void scan_reduce(const int* __restrict__ cnt,
                                                      int* __restrict__ bsum, int N) {
  __shared__ int sd[SCAN_T];
  int base = blockIdx.x * SCAN_CHUNK;
  int s = 0;
  for (int i = threadIdx.x; i < SCAN_CHUNK; i += SCAN_T) {
    int idx = base + i;
    s += (idx < N) ? cnt[idx] : 0;
  }
  sd[threadIdx.x] = s;
  __syncthreads();
  for (int off = 128; off > 0; off >>= 1) {
    if (threadIdx.x < off) sd[threadIdx.x] += sd[threadIdx.x + off];
    __syncthreads();
  }
  if (threadIdx.x == 0) bsum[blockIdx.x] = sd[0];
}

// scan_final also derives its block offset from bsum in-LDS (NB<=256).
__global__ __launch_bounds__(SCAN_T) void scan_final(const int* __restrict__ cnt,
                                                     const int* __restrict__ bsum,
                                                     int* __restrict__ offs,
                                                     int* __restrict__ cursor, int N,
                                                     int NB) {
  __shared__ int a[SCAN_T], b[SCAN_T];
  int t = threadIdx.x;
  // exclusive block offset = sum_{i<blockIdx} bsum[i]
  a[t] = (t < blockIdx.x && t < NB) ? bsum[t] : 0;
  __syncthreads();
  for (int off = 128; off > 0; off >>= 1) {
    if (t < off) a[t] += a[t + off];
    __syncthreads();
  }
  int boff = a[0];
  __syncthreads();
  int base = blockIdx.x * SCAN_CHUNK;
  int mybase = base + t * SCAN_I;
  int loc[SCAN_I];
  int s = 0;
#pragma unroll
  for (int i = 0; i < SCAN_I; i++) {
    int idx = mybase + i;
    int v = (idx < N) ? cnt[idx] : 0;
    loc[i] = s;
    s += v;
  }
  a[t] = s;
  __syncthreads();
  int* src = a;
  int* dst = b;
  for (int off = 1; off < SCAN_T; off <<= 1) {
    int val = src[t] + ((t >= off) ? src[t - off] : 0);
    dst[t] = val;
    __syncthreads();
    int* tmp = src; src = dst; dst = tmp;
  }
  int texcl = src[t] - s;
#pragma unroll
  for (int i = 0; i < SCAN_I; i++) {
    int idx = mybase + i;
    if (idx < N) {
      int o = boff + texcl + loc[i];
      offs[idx] = o;
      cursor[idx] = o;
    }
  }
}

// Partitioned scatter; stores PRE-SCALED byte offsets (c<<7) so node_pass
// addressing is a single 32-bit OR.
__global__ __launch_bounds__(256) void scatter_part(const int* __restrict__ rowi,
                                                    const int* __restrict__ coli,
                                                    int* __restrict__ cursor,
                                                    int* __restrict__ srcs, int E, int N) {
  int g = blockIdx.x & 7;
  int lo = (int)(((long long)g * N) >> 3);
  int hi = (int)(((long long)(g + 1) * N) >> 3);
  int stride = (gridDim.x >> 3) * blockDim.x;
  for (int i = (blockIdx.x >> 3) * blockDim.x + threadIdx.x; i < E; i += stride) {
    int r = rowi[i];
    if (r >= lo && r < hi) {
      int pos = atomicAdd(&cursor[r], 1);
      srcs[pos] = coli[i] << 7;
    }
  }
}

// -------- Node pass: one wave/node, 2 ch/lane, 2 edge streams, 8-unroll ----
#define EDGE_STEP(u)                                            \
  {                                                             \
    f32x2 j = upk(u);                                           \
    f32x2 s = hiv + j;                                          \
    f32x2 mx, mn;                                               \
    mx.x = fmaxf(s.x, 0.f); mx.y = fmaxf(s.y, 0.f);             \
    mn.x = fminf(s.x, 0.f); mn.y = fminf(s.y, 0.f);             \
    f32x2 d = (mn * NEG_SLOPE + mx) * attv;                     \
    float al = d.x + d.y;                                       \
    al += __shfl_xor(al, 1);                                    \
    al += __shfl_xor(al, 2);                                    \
    al += __shfl_xor(al, 4);                                    \
    float p = __expf(al);                                       \
    acc += j * p;                                               \
    den += p;                                                   \
  }

__global__ __launch_bounds__(256) void node_pass(const unsigned short* __restrict__ hb,
                                                 const int* __restrict__ offs,
                                                 const int* __restrict__ rowend,
                                                 const int* __restrict__ srcs,
                                                 const float* __restrict__ att,
                                                 const float* __restrict__ bias,
                                                 float* __restrict__ out, int N) {
  int w = (blockIdx.x * blockDim.x + threadIdx.x) >> 6;
  if (w >= N) return;
  const int lane = threadIdx.x & 63;
  const int lr = lane & 31;
  const int half = lane >> 5;
  const char* hbc = (const char*)hb;
  const unsigned loff = (unsigned)(lr << 2);
  const f32x2 attv = *(const f32x2*)(att + 2 * lr);
  const unsigned selfoff = ((unsigned)w << 7) | loff;
  const f32x2 hiv = upk(*(const unsigned*)(hbc + selfoff));
  f32x2 acc;
  float den;
  {  // self loop (half 0 contributes)
    f32x2 s = hiv + hiv;
    f32x2 mx, mn;
    mx.x = fmaxf(s.x, 0.f); mx.y = fmaxf(s.y, 0.f);
    mn.x = fminf(s.x, 0.f); mn.y = fminf(s.y, 0.f);
    f32x2 d = (mn * NEG_SLOPE + mx) * attv;
    float al = d.x + d.y;
    al += __shfl_xor(al, 1);
    al += __shfl_xor(al, 2);
    al += __shfl_xor(al, 4);
    float p = half ? 0.f : __expf(al);
    acc = hiv * p;
    den = p;
  }
  int k = offs[w];
  const int k1 = rowend[w];
  for (; k + 8 <= k1; k += 8) {
    unsigned o0 = (unsigned)srcs[k + half] | loff;
    unsigned o1 = (unsigned)srcs[k + 2 + half] | loff;
    unsigned o2 = (unsigned)srcs[k + 4 + half] | loff;
    unsigned o3 = (unsigned)srcs[k + 6 + half] | loff;
    unsigned u0 = *(const unsigned*)(hbc + o0);
    unsigned u1 = *(const unsigned*)(hbc + o1);
    unsigned u2 = *(const unsigned*)(hbc + o2);
    unsigned u3 = *(const unsigned*)(hbc + o3);
    EDGE_STEP(u0);
    EDGE_STEP(u1);
    EDGE_STEP(u2);
    EDGE_STEP(u3);
  }
  for (; k < k1; k += 2) {
    int kk = k + half;
    bool act = kk < k1;
    unsigned off = (act ? (unsigned)srcs[kk] : ((unsigned)w << 7)) | loff;
    unsigned u = *(const unsigned*)(hbc + off);
    f32x2 j = upk(u);
    f32x2 s = hiv + j;
    f32x2 mx, mn;
    mx.x = fmaxf(s.x, 0.f); mx.y = fmaxf(s.y, 0.f);
    mn.x = fminf(s.x, 0.f); mn.y = fminf(s.y, 0.f);
    f32x2 d = (mn * NEG_SLOPE + mx) * attv;
    float al = d.x + d.y;
    al += __shfl_xor(al, 1);
    al += __shfl_xor(al, 2);
    al += __shfl_xor(al, 4);
    float p = act ? __expf(al) : 0.f;
    acc += j * p;
    den += p;
  }
  acc.x += __shfl_xor(acc.x, 32);
  acc.y += __shfl_xor(acc.y, 32);
  den += __shfl_xor(den, 32);
  if (!half) {
    float inv = 1.0f / (den + 1e-16f);
    f32x2 bv = *(const f32x2*)(bias + 2 * lr);
    f32x2 o = acc * inv + bv;
    *(f32x2*)(out + (size_t)w * 64 + 2 * lr) = o;
  }
}

extern "C" void kernel_launch(void* const* d_in, const int* in_sizes, int n_in,
                              void* d_out, int out_size, void* d_ws, size_t ws_size,
                              hipStream_t stream) {
  const float* x = (const float*)d_in[0];
  const int* eidx = (const int*)d_in[1];  // int32 per harness conversion
  const float* W = (const float*)d_in[2];
  const float* att = (const float*)d_in[3];
  const float* bias = (const float*)d_in[4];
  float* out = (float*)d_out;

  const int N = in_sizes[0] / 128;
  const int E = in_sizes[1] / 2;
  const int NB = (N + SCAN_CHUNK - 1) / SCAN_CHUNK;

  unsigned short* hb = (unsigned short*)d_ws;      // N*64*2 = 12.8 MB
  int* cnt = (int*)(hb + (size_t)N * 64);          // N*4
  int* offs = cnt + N;                             // N*4
  int* cursor = offs + N;                          // N*4
  int* srcs = cursor + N;                          // E*4
  int* bsum = srcs + E;                            // NB*4

  hipMemsetAsync(cnt, 0, (size_t)N * sizeof(int), stream);

  gemm_xw<<<(N * 4 + 255) / 256, 256, 0, stream>>>(x, W, hb, N);
  hist_rows<<<2048, 256, 0, stream>>>(eidx, cnt, E, N);
  scan_reduce<<<NB, SCAN_T, 0, stream>>>(cnt, bsum, N);
  scan_final<<<NB, SCAN_T, 0, stream>>>(cnt, bsum, offs, cursor, N, NB);
  scatter_part<<<2048, 256, 0, stream>>>(eidx, eidx + E, cursor, srcs, E, N);
  node_pass<<<(N * 64 + 255) / 256, 256, 0, stream>>>(hb, offs, cursor, srcs, att, bias,
                                                      out, N);
}

// Round 6
// 153.187 us; speedup vs baseline: 3.2537x; 1.6814x over previous
//
#include <hip/hip_runtime.h>

#define NEG_SLOPE 0.2f

typedef float f32x2 __attribute__((ext_vector_type(2)));

// ---- bf16 helpers (raw-bit, RNE) ----
__device__ __forceinline__ unsigned short f2bf(float f) {
  union { float f; unsigned u; } v; v.f = f;
  unsigned r = v.u + 0x7fff + ((v.u >> 16) & 1);
  return (unsigned short)(r >> 16);
}
__device__ __forceinline__ unsigned pkbf(float a, float b) {
  return (unsigned)f2bf(a) | ((unsigned)f2bf(b) << 16);
}
__device__ __forceinline__ f32x2 upk(unsigned u) {
  union { unsigned u; float f; } lo, hi;
  lo.u = u << 16;
  hi.u = u & 0xffff0000u;
  f32x2 r;
  r.x = lo.f;
  r.y = hi.f;
  return r;
}

// -------- GEMM: hb[N,64](bf16) = x[N,128] @ W[128,64] --------
// 4 threads per row, 16 cols each -> 400K threads (6 waves/SIMD).
__global__ __launch_bounds__(256) void gemm_xw(const float* __restrict__ x,
                                               const float* __restrict__ W,
                                               unsigned short* __restrict__ hb, int N) {
  __shared__ float Wl[128 * 64];
  {
    const float4* Wv = (const float4*)W;
    float4* Wlv = (float4*)Wl;
    for (int i = threadIdx.x; i < 128 * 16; i += 256) Wlv[i] = Wv[i];
  }
  __syncthreads();
  int t = blockIdx.x * 256 + threadIdx.x;
  int r = t >> 2;
  if (r >= N) return;
  const int cg = (t & 3) * 16;
  float4 acc[4];
#pragma unroll
  for (int i = 0; i < 4; i++) acc[i] = make_float4(0.f, 0.f, 0.f, 0.f);
  const float4* xr = (const float4*)(x + (size_t)r * 128);
#pragma unroll 4
  for (int kq = 0; kq < 32; kq++) {
    float4 xv = xr[kq];
#pragma unroll
    for (int kk = 0; kk < 4; kk++) {
      float xs = (kk == 0) ? xv.x : (kk == 1) ? xv.y : (kk == 2) ? xv.z : xv.w;
      const float4* wrow = (const float4*)(&Wl[(kq * 4 + kk) * 64 + cg]);
#pragma unroll
      for (int c4 = 0; c4 < 4; c4++) {
        float4 wv = wrow[c4];
        acc[c4].x = fmaf(xs, wv.x, acc[c4].x);
        acc[c4].y = fmaf(xs, wv.y, acc[c4].y);
        acc[c4].z = fmaf(xs, wv.z, acc[c4].z);
        acc[c4].w = fmaf(xs, wv.w, acc[c4].w);
      }
    }
  }
  unsigned short* hp = hb + (size_t)r * 64 + cg;
  uint4 o0, o1;
  o0.x = pkbf(acc[0].x, acc[0].y); o0.y = pkbf(acc[0].z, acc[0].w);
  o0.z = pkbf(acc[1].x, acc[1].y); o0.w = pkbf(acc[1].z, acc[1].w);
  o1.x = pkbf(acc[2].x, acc[2].y); o1.y = pkbf(acc[2].z, acc[2].w);
  o1.z = pkbf(acc[3].x, acc[3].y); o1.w = pkbf(acc[3].z, acc[3].w);
  *(uint4*)hp = o0;
  *(uint4*)(hp + 8) = o1;
}

// -------- Pass 1: bucket edges by row>>9 --------
// One block per 2048-edge tile. LDS per-bucket counts -> 196 global atomic
// reserves per tile -> packed (rlo<<17|col) writes into slack bucket regions.
#define TILE 2048
#define NBKT_MAX 256

__global__ __launch_bounds__(256) void bucket_pass(const int* __restrict__ rowi,
                                                   const int* __restrict__ coli,
                                                   int* __restrict__ bucket_fill,
                                                   unsigned* __restrict__ bucket_arr,
                                                   int E, int C, int NBKT) {
  __shared__ int cnt[NBKT_MAX];
  __shared__ int base[NBKT_MAX];
  const int t = threadIdx.x;
  const int tile0 = blockIdx.x * TILE;
  for (int i = t; i < NBKT_MAX; i += 256) cnt[i] = 0;
  __syncthreads();
  unsigned pk[8];
  int bk[8];
#pragma unroll
  for (int j = 0; j < 8; j++) {
    int i = tile0 + j * 256 + t;
    if (i < E) {
      int r = rowi[i];
      int c = coli[i];
      bk[j] = r >> 9;
      pk[j] = ((unsigned)(r & 511) << 17) | (unsigned)c;
      atomicAdd(&cnt[bk[j]], 1);
    } else {
      bk[j] = -1;
    }
  }
  __syncthreads();
  if (t < NBKT) {
    int n = cnt[t];
    base[t] = (n > 0) ? atomicAdd(&bucket_fill[t], n) : 0;
    cnt[t] = 0;  // reuse as local cursor
  }
  __syncthreads();
#pragma unroll
  for (int j = 0; j < 8; j++) {
    if (bk[j] >= 0) {
      int lp = atomicAdd(&cnt[bk[j]], 1);
      int pos = base[bk[j]] + lp;
      if (pos < C) bucket_arr[bk[j] * C + pos] = pk[j];
    }
  }
}

// -------- Pass 2: per-bucket counting sort -> CSR (in-place) --------
// One block per bucket. Stage bucket in LDS, 512-entry hist+scan, write
// offs/rowend (slack layout b*C+excl, gaps never read), scatter col<<7
// back over own bucket range (safe: staged in LDS first).
#define STAGE_CAP 10240

__global__ __launch_bounds__(256) void csr_pass(unsigned* __restrict__ bucket_arr,
                                                const int* __restrict__ bucket_fill,
                                                int* __restrict__ offs,
                                                int* __restrict__ rowend,
                                                int C, int N) {
  __shared__ unsigned stage[STAGE_CAP];
  __shared__ int hist[512], excl[512], pairs[256];
  const int t = threadIdx.x;
  const int b = blockIdx.x;
  const int bb = b * C;
  const int nb = min(bucket_fill[b], C);
  for (int i = t; i < 512; i += 256) hist[i] = 0;
  for (int i = t; i < nb; i += 256) stage[i] = bucket_arr[bb + i];
  __syncthreads();
  for (int i = t; i < nb; i += 256) atomicAdd(&hist[stage[i] >> 17], 1);
  __syncthreads();
  // exclusive scan over 512 via 256 pair-sums (Hillis-Steele)
  int h0 = hist[2 * t], h1 = hist[2 * t + 1];
  int ps = h0 + h1;
  pairs[t] = ps;
  __syncthreads();
  for (int off = 1; off < 256; off <<= 1) {
    int val = pairs[t] + ((t >= off) ? pairs[t - off] : 0);
    __syncthreads();
    pairs[t] = val;
    __syncthreads();
  }
  int pexcl = pairs[t] - ps;
  excl[2 * t] = pexcl;
  excl[2 * t + 1] = pexcl + h0;
  __syncthreads();
  const int r0 = b << 9;
  for (int r = t; r < 512; r += 256) {
    int gr = r0 + r;
    if (gr < N) {
      int o = bb + excl[r];
      offs[gr] = o;
      rowend[gr] = o + hist[r];
    }
  }
  __syncthreads();
  for (int i = t; i < nb; i += 256) {
    unsigned pk = stage[i];
    int r = pk >> 17;
    int lp = atomicAdd(&excl[r], 1);
    bucket_arr[bb + lp] = (pk & 0x1FFFFu) << 7;  // pre-scaled byte offset
  }
}

// -------- Node pass: one wave/node, 2 ch/lane, 2 edge streams, 8-unroll ----
#define EDGE_STEP(u)                                            \
  {                                                             \
    f32x2 j = upk(u);                                           \
    f32x2 s = hiv + j;                                          \
    f32x2 mx, mn;                                               \
    mx.x = fmaxf(s.x, 0.f); mx.y = fmaxf(s.y, 0.f);             \
    mn.x = fminf(s.x, 0.f); mn.y = fminf(s.y, 0.f);             \
    f32x2 d = (mn * NEG_SLOPE + mx) * attv;                     \
    float al = d.x + d.y;                                       \
    al += __shfl_xor(al, 1);                                    \
    al += __shfl_xor(al, 2);                                    \
    al += __shfl_xor(al, 4);                                    \
    float p = __expf(al);                                       \
    acc += j * p;                                               \
    den += p;                                                   \
  }

__global__ __launch_bounds__(256) void node_pass(const unsigned short* __restrict__ hb,
                                                 const int* __restrict__ offs,
                                                 const int* __restrict__ rowend,
                                                 const unsigned* __restrict__ srcs,
                                                 const float* __restrict__ att,
                                                 const float* __restrict__ bias,
                                                 float* __restrict__ out, int N) {
  int w = (blockIdx.x * blockDim.x + threadIdx.x) >> 6;
  if (w >= N) return;
  const int lane = threadIdx.x & 63;
  const int lr = lane & 31;
  const int half = lane >> 5;
  const char* hbc = (const char*)hb;
  const unsigned loff = (unsigned)(lr << 2);
  const f32x2 attv = *(const f32x2*)(att + 2 * lr);
  const unsigned selfoff = ((unsigned)w << 7) | loff;
  const f32x2 hiv = upk(*(const unsigned*)(hbc + selfoff));
  f32x2 acc;
  float den;
  {  // self loop (half 0 contributes)
    f32x2 s = hiv + hiv;
    f32x2 mx, mn;
    mx.x = fmaxf(s.x, 0.f); mx.y = fmaxf(s.y, 0.f);
    mn.x = fminf(s.x, 0.f); mn.y = fminf(s.y, 0.f);
    f32x2 d = (mn * NEG_SLOPE + mx) * attv;
    float al = d.x + d.y;
    al += __shfl_xor(al, 1);
    al += __shfl_xor(al, 2);
    al += __shfl_xor(al, 4);
    float p = half ? 0.f : __expf(al);
    acc = hiv * p;
    den = p;
  }
  int k = offs[w];
  const int k1 = rowend[w];
  for (; k + 8 <= k1; k += 8) {
    unsigned o0 = srcs[k + half] | loff;
    unsigned o1 = srcs[k + 2 + half] | loff;
    unsigned o2 = srcs[k + 4 + half] | loff;
    unsigned o3 = srcs[k + 6 + half] | loff;
    unsigned u0 = *(const unsigned*)(hbc + o0);
    unsigned u1 = *(const unsigned*)(hbc + o1);
    unsigned u2 = *(const unsigned*)(hbc + o2);
    unsigned u3 = *(const unsigned*)(hbc + o3);
    EDGE_STEP(u0);
    EDGE_STEP(u1);
    EDGE_STEP(u2);
    EDGE_STEP(u3);
  }
  for (; k < k1; k += 2) {
    int kk = k + half;
    bool act = kk < k1;
    unsigned off = (act ? srcs[kk] : ((unsigned)w << 7)) | loff;
    unsigned u = *(const unsigned*)(hbc + off);
    f32x2 j = upk(u);
    f32x2 s = hiv + j;
    f32x2 mx, mn;
    mx.x = fmaxf(s.x, 0.f); mx.y = fmaxf(s.y, 0.f);
    mn.x = fminf(s.x, 0.f); mn.y = fminf(s.y, 0.f);
    f32x2 d = (mn * NEG_SLOPE + mx) * attv;
    float al = d.x + d.y;
    al += __shfl_xor(al, 1);
    al += __shfl_xor(al, 2);
    al += __shfl_xor(al, 4);
    float p = act ? __expf(al) : 0.f;
    acc += j * p;
    den += p;
  }
  acc.x += __shfl_xor(acc.x, 32);
  acc.y += __shfl_xor(acc.y, 32);
  den += __shfl_xor(den, 32);
  if (!half) {
    float inv = 1.0f / (den + 1e-16f);
    f32x2 bv = *(const f32x2*)(bias + 2 * lr);
    f32x2 o = acc * inv + bv;
    *(f32x2*)(out + (size_t)w * 64 + 2 * lr) = o;
  }
}

extern "C" void kernel_launch(void* const* d_in, const int* in_sizes, int n_in,
                              void* d_out, int out_size, void* d_ws, size_t ws_size,
                              hipStream_t stream) {
  const float* x = (const float*)d_in[0];
  const int* eidx = (const int*)d_in[1];  // int32 per harness conversion
  const float* W = (const float*)d_in[2];
  const float* att = (const float*)d_in[3];
  const float* bias = (const float*)d_in[4];
  float* out = (float*)d_out;

  const int N = in_sizes[0] / 128;
  const int E = in_sizes[1] / 2;
  const int NBKT = (N + 511) >> 9;      // 196 for N=100K (needs N <= 131072)
  int C = (E + NBKT - 1) / NBKT;        // avg bucket size
  C = C + C / 8 + 64;                   // ~12.5% slack (11+ sigma for random rows)
  C = (C + 15) & ~15;
  if (C > STAGE_CAP) C = STAGE_CAP;

  unsigned short* hb = (unsigned short*)d_ws;          // N*64*2 = 12.8 MB
  int* bucket_fill = (int*)(hb + (size_t)N * 64);      // NBKT_MAX ints
  int* offs = bucket_fill + NBKT_MAX;                  // N ints
  int* rowend = offs + N;                              // N ints
  unsigned* bucket_arr = (unsigned*)(rowend + N);      // NBKT*C u32 (~7.3 MB)

  hipMemsetAsync(bucket_fill, 0, NBKT_MAX * sizeof(int), stream);

  gemm_xw<<<(N * 4 + 255) / 256, 256, 0, stream>>>(x, W, hb, N);
  bucket_pass<<<(E + TILE - 1) / TILE, 256, 0, stream>>>(eidx, eidx + E, bucket_fill,
                                                         bucket_arr, E, C, NBKT);
  csr_pass<<<NBKT, 256, 0, stream>>>(bucket_arr, bucket_fill, offs, rowend, C, N);
  node_pass<<<(N * 64 + 255) / 256, 256, 0, stream>>>(hb, offs, rowend, bucket_arr, att,
                                                      bias, out, N);
}

// Round 7
// 120.302 us; speedup vs baseline: 4.1431x; 1.2734x over previous
//
#include <hip/hip_runtime.h>

#define NEG_SLOPE 0.2f

typedef float f32x2 __attribute__((ext_vector_type(2)));
typedef float f32x4 __attribute__((ext_vector_type(4)));
typedef short bf16x8 __attribute__((ext_vector_type(8)));

// ---- bf16 helpers (raw-bit, RNE) ----
__device__ __forceinline__ unsigned short f2bf(float f) {
  union { float f; unsigned u; } v; v.f = f;
  unsigned r = v.u + 0x7fff + ((v.u >> 16) & 1);
  return (unsigned short)(r >> 16);
}
__device__ __forceinline__ float bf2f(unsigned short u) {
  union { unsigned u; float f; } v; v.u = ((unsigned)u) << 16;
  return v.f;
}
__device__ __forceinline__ unsigned pkbf(float a, float b) {
  return (unsigned)f2bf(a) | ((unsigned)f2bf(b) << 16);
}
__device__ __forceinline__ f32x4 upk4(uint2 u) {
  union { unsigned u; float f; } a, b, c, d;
  a.u = u.x << 16; b.u = u.x & 0xffff0000u;
  c.u = u.y << 16; d.u = u.y & 0xffff0000u;
  f32x4 r; r.x = a.f; r.y = b.f; r.z = c.f; r.w = d.f;
  return r;
}

// -------- MFMA GEMM: hb[N,64](bf16) = x[N,128] @ W[128,64] --------
// mfma_f32_16x16x32_bf16. A: row=l&15, k=(l>>4)*8+j (8 contiguous k).
// B: col=l&15, k=(l>>4)*8+j. C: col=l&15, row=(l>>4)*4+reg.
// x split hi+lo bf16 (2 MFMAs) so dot error ~ W-quantization only.
__global__ __launch_bounds__(256) void gemm_mfma(const float* __restrict__ x,
                                                 const float* __restrict__ W,
                                                 unsigned short* __restrict__ hb, int N) {
  __shared__ uint4 Bl[1024];  // [ct*4+kt][lane] : 16B B-fragments
  const int t = threadIdx.x;
  {
    const int l = t & 63;
    const int kt = (t >> 6) & 3;
    const int kb = kt * 32 + ((l >> 4) * 8);
    const int cb = l & 15;
#pragma unroll
    for (int ct = 0; ct < 4; ct++) {
      const float* wp = W + (size_t)kb * 64 + ct * 16 + cb;
      unsigned p[4];
#pragma unroll
      for (int jj = 0; jj < 4; jj++)
        p[jj] = pkbf(wp[(2 * jj) * 64], wp[(2 * jj + 1) * 64]);
      Bl[(ct * 4 + kt) * 64 + l] = make_uint4(p[0], p[1], p[2], p[3]);
    }
  }
  __syncthreads();
  const int l = t & 63;
  const int wv = t >> 6;
  union BU { bf16x8 v; uint4 q; };
  BU b[4][4];
#pragma unroll
  for (int ct = 0; ct < 4; ct++)
#pragma unroll
    for (int kt = 0; kt < 4; kt++) b[ct][kt].q = Bl[(ct * 4 + kt) * 64 + l];

  const int rowbase0 = blockIdx.x * 256 + wv * 64;
#pragma unroll
  for (int rt = 0; rt < 4; rt++) {
    const int rbase = rowbase0 + rt * 16;
    int rl = rbase + (l & 15);
    if (rl >= N) rl = N - 1;
    const float* xp = x + (size_t)rl * 128 + ((l >> 4) * 8);
    BU ah[4], alo[4];
#pragma unroll
    for (int kt = 0; kt < 4; kt++) {
      float f[8];
      float4 v0 = *(const float4*)(xp + kt * 32);
      float4 v1 = *(const float4*)(xp + kt * 32 + 4);
      f[0] = v0.x; f[1] = v0.y; f[2] = v0.z; f[3] = v0.w;
      f[4] = v1.x; f[5] = v1.y; f[6] = v1.z; f[7] = v1.w;
      unsigned short hs[8], ls[8];
#pragma unroll
      for (int j = 0; j < 8; j++) {
        hs[j] = f2bf(f[j]);
        ls[j] = f2bf(f[j] - bf2f(hs[j]));
      }
      ah[kt].q = make_uint4(hs[0] | (hs[1] << 16), hs[2] | (hs[3] << 16),
                            hs[4] | (hs[5] << 16), hs[6] | (hs[7] << 16));
      alo[kt].q = make_uint4(ls[0] | (ls[1] << 16), ls[2] | (ls[3] << 16),
                             ls[4] | (ls[5] << 16), ls[6] | (ls[7] << 16));
    }
#pragma unroll
    for (int ct = 0; ct < 4; ct++) {
      f32x4 acc = {0.f, 0.f, 0.f, 0.f};
#pragma unroll
      for (int kt = 0; kt < 4; kt++) {
        acc = __builtin_amdgcn_mfma_f32_16x16x32_bf16(ah[kt].v, b[ct][kt].v, acc, 0, 0, 0);
        acc = __builtin_amdgcn_mfma_f32_16x16x32_bf16(alo[kt].v, b[ct][kt].v, acc, 0, 0, 0);
      }
#pragma unroll
      for (int j = 0; j < 4; j++) {
        float v = acc[j];
        float pv = __shfl_xor(v, 1);
        int row = rbase + (l >> 4) * 4 + j;
        if (!(l & 1) && row < N) {
          *(unsigned*)((char*)hb + (size_t)row * 128 + ct * 32 + (l & 15) * 2) =
              pkbf(v, pv);
        }
      }
    }
  }
}

// -------- Pass 1: bucket edges by row>>9 --------
#define TILE 2048
#define NBKT_MAX 256

__global__ __launch_bounds__(256) void bucket_pass(const int* __restrict__ rowi,
                                                   const int* __restrict__ coli,
                                                   int* __restrict__ bucket_fill,
                                                   unsigned* __restrict__ bucket_arr,
                                                   int E, int C, int NBKT) {
  __shared__ int cnt[NBKT_MAX];
  __shared__ int base[NBKT_MAX];
  const int t = threadIdx.x;
  const int tile0 = blockIdx.x * TILE;
  for (int i = t; i < NBKT_MAX; i += 256) cnt[i] = 0;
  __syncthreads();
  unsigned pk[8];
  int bk[8];
#pragma unroll
  for (int j = 0; j < 8; j++) {
    int i = tile0 + j * 256 + t;
    if (i < E) {
      int r = rowi[i];
      int c = coli[i];
      bk[j] = r >> 9;
      pk[j] = ((unsigned)(r & 511) << 17) | (unsigned)c;
      atomicAdd(&cnt[bk[j]], 1);
    } else {
      bk[j] = -1;
    }
  }
  __syncthreads();
  if (t < NBKT) {
    int n = cnt[t];
    base[t] = (n > 0) ? atomicAdd(&bucket_fill[t], n) : 0;
    cnt[t] = 0;  // reuse as local cursor
  }
  __syncthreads();
#pragma unroll
  for (int j = 0; j < 8; j++) {
    if (bk[j] >= 0) {
      int lp = atomicAdd(&cnt[bk[j]], 1);
      int pos = base[bk[j]] + lp;
      if (pos < C) bucket_arr[bk[j] * C + pos] = pk[j];
    }
  }
}

// -------- Pass 2: per-bucket counting sort -> CSR (in-place) --------
#define STAGE_CAP 10240

__global__ __launch_bounds__(256) void csr_pass(unsigned* __restrict__ bucket_arr,
                                                const int* __restrict__ bucket_fill,
                                                int* __restrict__ offs,
                                                int* __restrict__ rowend,
                                                int C, int N) {
  __shared__ unsigned stage[STAGE_CAP];
  __shared__ int hist[512], excl[512], pairs[256];
  const int t = threadIdx.x;
  const int b = blockIdx.x;
  const int bb = b * C;
  const int nb = min(bucket_fill[b], C);
  for (int i = t; i < 512; i += 256) hist[i] = 0;
  for (int i = t; i < nb; i += 256) stage[i] = bucket_arr[bb + i];
  __syncthreads();
  for (int i = t; i < nb; i += 256) atomicAdd(&hist[stage[i] >> 17], 1);
  __syncthreads();
  int h0 = hist[2 * t], h1 = hist[2 * t + 1];
  int ps = h0 + h1;
  pairs[t] = ps;
  __syncthreads();
  for (int off = 1; off < 256; off <<= 1) {
    int val = pairs[t] + ((t >= off) ? pairs[t - off] : 0);
    __syncthreads();
    pairs[t] = val;
    __syncthreads();
  }
  int pexcl = pairs[t] - ps;
  excl[2 * t] = pexcl;
  excl[2 * t + 1] = pexcl + h0;
  __syncthreads();
  const int r0 = b << 9;
  for (int r = t; r < 512; r += 256) {
    int gr = r0 + r;
    if (gr < N) {
      int o = bb + excl[r];
      offs[gr] = o;
      rowend[gr] = o + hist[r];
    }
  }
  __syncthreads();
  for (int i = t; i < nb; i += 256) {
    unsigned pk = stage[i];
    int r = pk >> 17;
    int lp = atomicAdd(&excl[r], 1);
    bucket_arr[bb + lp] = (pk & 0x1FFFFu) << 7;  // pre-scaled byte offset
  }
}

// -------- Node pass: one wave/node, 4 ch/lane, 4 edge streams --------
// lane = q*16+lr: lr owns channels 4lr..4lr+3 (head = lr>>2), quarter q owns
// edge stream q. leaky*att folded: attA*s + attB*|s| (attA=0.6att, attB=0.4att).
#define ESTEP(u)                                        \
  {                                                     \
    f32x4 jv = upk4(u);                                 \
    f32x4 s = hiv + jv;                                 \
    f32x4 as;                                           \
    as.x = fabsf(s.x); as.y = fabsf(s.y);               \
    as.z = fabsf(s.z); as.w = fabsf(s.w);               \
    f32x4 d = s * attA + as * attB;                     \
    float al = (d.x + d.y) + (d.z + d.w);               \
    al += __shfl_xor(al, 1);                            \
    al += __shfl_xor(al, 2);                            \
    float p = __expf(al);                               \
    acc += jv * p;                                      \
    den += p;                                           \
  }

__global__ __launch_bounds__(256) void node_pass(const unsigned short* __restrict__ hb,
                                                 const int* __restrict__ offs,
                                                 const int* __restrict__ rowend,
                                                 const unsigned* __restrict__ srcs,
                                                 const float* __restrict__ att,
                                                 const float* __restrict__ bias,
                                                 float* __restrict__ out, int N) {
  int w = (blockIdx.x * blockDim.x + threadIdx.x) >> 6;
  if (w >= N) return;
  const int lane = threadIdx.x & 63;
  const int lr = lane & 15;
  const int q = lane >> 4;
  const char* hbc = (const char*)hb;
  const unsigned loff = (unsigned)(lr << 3);
  const f32x4 attv = *(const f32x4*)(att + 4 * lr);
  const f32x4 attA = attv * 0.6f;
  const f32x4 attB = attv * 0.4f;
  const f32x4 hiv = upk4(*(const uint2*)(hbc + (((unsigned)w << 7) | loff)));
  f32x4 acc;
  float den;
  {  // self loop (stream 0 contributes)
    f32x4 s = hiv + hiv;
    f32x4 as;
    as.x = fabsf(s.x); as.y = fabsf(s.y);
    as.z = fabsf(s.z); as.w = fabsf(s.w);
    f32x4 d = s * attA + as * attB;
    float al = (d.x + d.y) + (d.z + d.w);
    al += __shfl_xor(al, 1);
    al += __shfl_xor(al, 2);
    float p = (q == 0) ? __expf(al) : 0.f;
    acc = hiv * p;
    den = p;
  }
  int k = offs[w];
  const int k1 = rowend[w];
  for (; k + 8 <= k1; k += 8) {
    unsigned o0 = srcs[k + q] | loff;
    unsigned o1 = srcs[k + 4 + q] | loff;
    uint2 u0 = *(const uint2*)(hbc + o0);
    uint2 u1 = *(const uint2*)(hbc + o1);
    ESTEP(u0);
    ESTEP(u1);
  }
  for (; k < k1; k += 4) {
    int kk = k + q;
    bool act = kk < k1;
    unsigned o = (act ? srcs[kk] : ((unsigned)w << 7)) | loff;
    uint2 u = *(const uint2*)(hbc + o);
    f32x4 jv = upk4(u);
    f32x4 s = hiv + jv;
    f32x4 as;
    as.x = fabsf(s.x); as.y = fabsf(s.y);
    as.z = fabsf(s.z); as.w = fabsf(s.w);
    f32x4 d = s * attA + as * attB;
    float al = (d.x + d.y) + (d.z + d.w);
    al += __shfl_xor(al, 1);
    al += __shfl_xor(al, 2);
    float p = act ? __expf(al) : 0.f;
    acc += jv * p;
    den += p;
  }
  // combine 4 streams
  acc.x += __shfl_xor(acc.x, 16); acc.y += __shfl_xor(acc.y, 16);
  acc.z += __shfl_xor(acc.z, 16); acc.w += __shfl_xor(acc.w, 16);
  den += __shfl_xor(den, 16);
  acc.x += __shfl_xor(acc.x, 32); acc.y += __shfl_xor(acc.y, 32);
  acc.z += __shfl_xor(acc.z, 32); acc.w += __shfl_xor(acc.w, 32);
  den += __shfl_xor(den, 32);
  if (q == 0) {
    float inv = 1.0f / (den + 1e-16f);
    f32x4 bv = *(const f32x4*)(bias + 4 * lr);
    f32x4 o = acc * inv + bv;
    *(f32x4*)(out + (size_t)w * 64 + 4 * lr) = o;
  }
}

extern "C" void kernel_launch(void* const* d_in, const int* in_sizes, int n_in,
                              void* d_out, int out_size, void* d_ws, size_t ws_size,
                              hipStream_t stream) {
  const float* x = (const float*)d_in[0];
  const int* eidx = (const int*)d_in[1];  // int32 per harness conversion
  const float* W = (const float*)d_in[2];
  const float* att = (const float*)d_in[3];
  const float* bias = (const float*)d_in[4];
  float* out = (float*)d_out;

  const int N = in_sizes[0] / 128;
  const int E = in_sizes[1] / 2;
  const int NBKT = (N + 511) >> 9;
  int C = (E + NBKT - 1) / NBKT;
  C = C + C / 8 + 64;
  C = (C + 15) & ~15;
  if (C > STAGE_CAP) C = STAGE_CAP;

  unsigned short* hb = (unsigned short*)d_ws;          // N*64*2 = 12.8 MB
  int* bucket_fill = (int*)(hb + (size_t)N * 64);      // NBKT_MAX ints
  int* offs = bucket_fill + NBKT_MAX;                  // N ints
  int* rowend = offs + N;                              // N ints
  unsigned* bucket_arr = (unsigned*)(rowend + N);      // NBKT*C u32 (~7.3 MB)

  hipMemsetAsync(bucket_fill, 0, NBKT_MAX * sizeof(int), stream);

  gemm_mfma<<<(N + 255) / 256, 256, 0, stream>>>(x, W, hb, N);
  bucket_pass<<<(E + TILE - 1) / TILE, 256, 0, stream>>>(eidx, eidx + E, bucket_fill,
                                                         bucket_arr, E, C, NBKT);
  csr_pass<<<NBKT, 256, 0, stream>>>(bucket_arr, bucket_fill, offs, rowend, C, N);
  node_pass<<<(N * 64 + 255) / 256, 256, 0, stream>>>(hb, offs, rowend, bucket_arr, att,
                                                      bias, out, N);
}

// Round 8
// 115.669 us; speedup vs baseline: 4.3091x; 1.0401x over previous
//
#include <hip/hip_runtime.h>

#define NEG_SLOPE 0.2f

typedef float f32x2 __attribute__((ext_vector_type(2)));
typedef float f32x4 __attribute__((ext_vector_type(4)));
typedef short bf16x8 __attribute__((ext_vector_type(8)));

// ---- bf16 helpers (raw-bit, RNE) ----
__device__ __forceinline__ unsigned short f2bf(float f) {
  union { float f; unsigned u; } v; v.f = f;
  unsigned r = v.u + 0x7fff + ((v.u >> 16) & 1);
  return (unsigned short)(r >> 16);
}
__device__ __forceinline__ float bf2f(unsigned short u) {
  union { unsigned u; float f; } v; v.u = ((unsigned)u) << 16;
  return v.f;
}
__device__ __forceinline__ unsigned pkbf(float a, float b) {
  return (unsigned)f2bf(a) | ((unsigned)f2bf(b) << 16);
}
__device__ __forceinline__ f32x4 upk4(uint2 u) {
  union { unsigned u; float f; } a, b, c, d;
  a.u = u.x << 16; b.u = u.x & 0xffff0000u;
  c.u = u.y << 16; d.u = u.y & 0xffff0000u;
  f32x4 r; r.x = a.f; r.y = b.f; r.z = c.f; r.w = d.f;
  return r;
}

// -------- MFMA GEMM: hb[N,64](bf16) = x[N,128] @ W[128,64] --------
// mfma_f32_16x16x32_bf16. x split hi+lo bf16 (2 MFMAs) so dot error ~ W only.
__global__ __launch_bounds__(256) void gemm_mfma(const float* __restrict__ x,
                                                 const float* __restrict__ W,
                                                 unsigned short* __restrict__ hb, int N) {
  __shared__ uint4 Bl[1024];  // [ct*4+kt][lane] : 16B B-fragments
  const int t = threadIdx.x;
  {
    const int l = t & 63;
    const int kt = (t >> 6) & 3;
    const int kb = kt * 32 + ((l >> 4) * 8);
    const int cb = l & 15;
#pragma unroll
    for (int ct = 0; ct < 4; ct++) {
      const float* wp = W + (size_t)kb * 64 + ct * 16 + cb;
      unsigned p[4];
#pragma unroll
      for (int jj = 0; jj < 4; jj++)
        p[jj] = pkbf(wp[(2 * jj) * 64], wp[(2 * jj + 1) * 64]);
      Bl[(ct * 4 + kt) * 64 + l] = make_uint4(p[0], p[1], p[2], p[3]);
    }
  }
  __syncthreads();
  const int l = t & 63;
  const int wv = t >> 6;
  union BU { bf16x8 v; uint4 q; };
  BU b[4][4];
#pragma unroll
  for (int ct = 0; ct < 4; ct++)
#pragma unroll
    for (int kt = 0; kt < 4; kt++) b[ct][kt].q = Bl[(ct * 4 + kt) * 64 + l];

  const int rowbase0 = blockIdx.x * 256 + wv * 64;
#pragma unroll
  for (int rt = 0; rt < 4; rt++) {
    const int rbase = rowbase0 + rt * 16;
    int rl = rbase + (l & 15);
    if (rl >= N) rl = N - 1;
    const float* xp = x + (size_t)rl * 128 + ((l >> 4) * 8);
    BU ah[4], alo[4];
#pragma unroll
    for (int kt = 0; kt < 4; kt++) {
      float f[8];
      float4 v0 = *(const float4*)(xp + kt * 32);
      float4 v1 = *(const float4*)(xp + kt * 32 + 4);
      f[0] = v0.x; f[1] = v0.y; f[2] = v0.z; f[3] = v0.w;
      f[4] = v1.x; f[5] = v1.y; f[6] = v1.z; f[7] = v1.w;
      unsigned short hs[8], ls[8];
#pragma unroll
      for (int j = 0; j < 8; j++) {
        hs[j] = f2bf(f[j]);
        ls[j] = f2bf(f[j] - bf2f(hs[j]));
      }
      ah[kt].q = make_uint4(hs[0] | (hs[1] << 16), hs[2] | (hs[3] << 16),
                            hs[4] | (hs[5] << 16), hs[6] | (hs[7] << 16));
      alo[kt].q = make_uint4(ls[0] | (ls[1] << 16), ls[2] | (ls[3] << 16),
                             ls[4] | (ls[5] << 16), ls[6] | (ls[7] << 16));
    }
#pragma unroll
    for (int ct = 0; ct < 4; ct++) {
      f32x4 acc = {0.f, 0.f, 0.f, 0.f};
#pragma unroll
      for (int kt = 0; kt < 4; kt++) {
        acc = __builtin_amdgcn_mfma_f32_16x16x32_bf16(ah[kt].v, b[ct][kt].v, acc, 0, 0, 0);
        acc = __builtin_amdgcn_mfma_f32_16x16x32_bf16(alo[kt].v, b[ct][kt].v, acc, 0, 0, 0);
      }
#pragma unroll
      for (int j = 0; j < 4; j++) {
        float v = acc[j];
        float pv = __shfl_xor(v, 1);
        int row = rbase + (l >> 4) * 4 + j;
        if (!(l & 1) && row < N) {
          *(unsigned*)((char*)hb + (size_t)row * 128 + ct * 32 + (l & 15) * 2) =
              pkbf(v, pv);
        }
      }
    }
  }
}

// -------- Pass 1: bucket edges by row>>9 --------
#define TILE 4096
#define EPT 16
#define NBKT_MAX 256

__global__ __launch_bounds__(256) void bucket_pass(const int* __restrict__ rowi,
                                                   const int* __restrict__ coli,
                                                   int* __restrict__ bucket_fill,
                                                   unsigned* __restrict__ bucket_arr,
                                                   int E, int Cedge, int Ctot, int NBKT) {
  __shared__ int cnt[NBKT_MAX];
  __shared__ int base[NBKT_MAX];
  const int t = threadIdx.x;
  const int tile0 = blockIdx.x * TILE;
  for (int i = t; i < NBKT_MAX; i += 256) cnt[i] = 0;
  __syncthreads();
  unsigned pk[EPT];
  int bk[EPT];
#pragma unroll
  for (int j = 0; j < EPT; j++) {
    int i = tile0 + j * 256 + t;
    if (i < E) {
      int r = rowi[i];
      int c = coli[i];
      bk[j] = r >> 9;
      pk[j] = ((unsigned)(r & 511) << 17) | (unsigned)c;
      atomicAdd(&cnt[bk[j]], 1);
    } else {
      bk[j] = -1;
    }
  }
  __syncthreads();
  if (t < NBKT) {
    int n = cnt[t];
    base[t] = (n > 0) ? atomicAdd(&bucket_fill[t], n) : 0;
    cnt[t] = 0;  // reuse as local cursor
  }
  __syncthreads();
#pragma unroll
  for (int j = 0; j < EPT; j++) {
    if (bk[j] >= 0) {
      int lp = atomicAdd(&cnt[bk[j]], 1);
      int pos = base[bk[j]] + lp;
      if (pos < Cedge) bucket_arr[bk[j] * Ctot + pos] = pk[j];
    }
  }
}

// -------- Pass 2: per-bucket counting sort -> CSR (in-place) --------
// hist init = 1 per valid row (self-loop slot); self entry appended after
// the edge scatter. rowinfo[r] = {offs, end} packed int2.
#define STAGE_CAP 10240

__global__ __launch_bounds__(256) void csr_pass(unsigned* __restrict__ bucket_arr,
                                                const int* __restrict__ bucket_fill,
                                                int2* __restrict__ rowinfo,
                                                int Cedge, int Ctot, int N) {
  __shared__ unsigned stage[STAGE_CAP];
  __shared__ int hist[512], excl[512], pairs[256];
  const int t = threadIdx.x;
  const int b = blockIdx.x;
  const int bb = b * Ctot;
  const int r0 = b << 9;
  const int nb = min(bucket_fill[b], Cedge);
  for (int i = t; i < 512; i += 256) hist[i] = ((r0 + i) < N) ? 1 : 0;  // self slot
  for (int i = t; i < nb; i += 256) stage[i] = bucket_arr[bb + i];
  __syncthreads();
  for (int i = t; i < nb; i += 256) atomicAdd(&hist[stage[i] >> 17], 1);
  __syncthreads();
  int h0 = hist[2 * t], h1 = hist[2 * t + 1];
  int ps = h0 + h1;
  pairs[t] = ps;
  __syncthreads();
  for (int off = 1; off < 256; off <<= 1) {
    int val = pairs[t] + ((t >= off) ? pairs[t - off] : 0);
    __syncthreads();
    pairs[t] = val;
    __syncthreads();
  }
  int pexcl = pairs[t] - ps;
  excl[2 * t] = pexcl;
  excl[2 * t + 1] = pexcl + h0;
  __syncthreads();
  for (int r = t; r < 512; r += 256) {
    int gr = r0 + r;
    if (gr < N) {
      int o = bb + excl[r];
      rowinfo[gr] = make_int2(o, o + hist[r]);
    }
  }
  __syncthreads();
  for (int i = t; i < nb; i += 256) {
    unsigned pk = stage[i];
    int r = pk >> 17;
    int lp = atomicAdd(&excl[r], 1);
    bucket_arr[bb + lp] = (pk & 0x1FFFFu) << 7;  // pre-scaled byte offset
  }
  __syncthreads();
  // append self entries (cursor now = offs + nedges = last slot)
  for (int r = t; r < 512; r += 256) {
    int gr = r0 + r;
    if (gr < N) bucket_arr[bb + excl[r]] = (unsigned)gr << 7;
  }
}

// -------- Node pass: one wave/node, 4 ch/lane, 4 edge streams, 16-unroll ----
#define ESTEP(u)                                        \
  {                                                     \
    f32x4 jv = upk4(u);                                 \
    f32x4 s = hiv + jv;                                 \
    f32x4 as;                                           \
    as.x = fabsf(s.x); as.y = fabsf(s.y);               \
    as.z = fabsf(s.z); as.w = fabsf(s.w);               \
    f32x4 d = s * attA + as * attB;                     \
    float al = (d.x + d.y) + (d.z + d.w);               \
    al += __shfl_xor(al, 1);                            \
    al += __shfl_xor(al, 2);                            \
    float p = __expf(al);                               \
    acc += jv * p;                                      \
    den += p;                                           \
  }

__global__ __launch_bounds__(256) void node_pass(const unsigned short* __restrict__ hb,
                                                 const int2* __restrict__ rowinfo,
                                                 const unsigned* __restrict__ srcs,
                                                 const float* __restrict__ att,
                                                 const float* __restrict__ bias,
                                                 float* __restrict__ out, int N) {
  int w = (blockIdx.x * blockDim.x + threadIdx.x) >> 6;
  if (w >= N) return;
  const int lane = threadIdx.x & 63;
  const int lr = lane & 15;
  const int q = lane >> 4;
  const char* hbc = (const char*)hb;
  const unsigned loff = (unsigned)(lr << 3);
  const f32x4 attv = *(const f32x4*)(att + 4 * lr);
  const f32x4 attA = attv * 0.6f;
  const f32x4 attB = attv * 0.4f;
  const int2 oi = rowinfo[w];
  int k = oi.x;
  const int k1 = oi.y;
  const f32x4 hiv = upk4(*(const uint2*)(hbc + (((unsigned)w << 7) | loff)));
  f32x4 acc = {0.f, 0.f, 0.f, 0.f};
  float den = 0.f;
  for (; k + 16 <= k1; k += 16) {
    unsigned o0 = srcs[k + q] | loff;
    unsigned o1 = srcs[k + 4 + q] | loff;
    unsigned o2 = srcs[k + 8 + q] | loff;
    unsigned o3 = srcs[k + 12 + q] | loff;
    uint2 u0 = *(const uint2*)(hbc + o0);
    uint2 u1 = *(const uint2*)(hbc + o1);
    uint2 u2 = *(const uint2*)(hbc + o2);
    uint2 u3 = *(const uint2*)(hbc + o3);
    ESTEP(u0);
    ESTEP(u1);
    ESTEP(u2);
    ESTEP(u3);
  }
  for (; k + 4 <= k1; k += 4) {
    unsigned o = srcs[k + q] | loff;
    uint2 u = *(const uint2*)(hbc + o);
    ESTEP(u);
  }
  if (k < k1) {
    int kk = k + q;
    bool act = kk < k1;
    unsigned o = (act ? srcs[kk] : srcs[k]) | loff;
    uint2 u = *(const uint2*)(hbc + o);
    f32x4 jv = upk4(u);
    f32x4 s = hiv + jv;
    f32x4 as;
    as.x = fabsf(s.x); as.y = fabsf(s.y);
    as.z = fabsf(s.z); as.w = fabsf(s.w);
    f32x4 d = s * attA + as * attB;
    float al = (d.x + d.y) + (d.z + d.w);
    al += __shfl_xor(al, 1);
    al += __shfl_xor(al, 2);
    float p = act ? __expf(al) : 0.f;
    acc += jv * p;
    den += p;
  }
  // combine 4 streams
  acc.x += __shfl_xor(acc.x, 16); acc.y += __shfl_xor(acc.y, 16);
  acc.z += __shfl_xor(acc.z, 16); acc.w += __shfl_xor(acc.w, 16);
  den += __shfl_xor(den, 16);
  acc.x += __shfl_xor(acc.x, 32); acc.y += __shfl_xor(acc.y, 32);
  acc.z += __shfl_xor(acc.z, 32); acc.w += __shfl_xor(acc.w, 32);
  den += __shfl_xor(den, 32);
  if (q == 0) {
    float inv = 1.0f / (den + 1e-16f);
    f32x4 bv = *(const f32x4*)(bias + 4 * lr);
    f32x4 o = acc * inv + bv;
    *(f32x4*)(out + (size_t)w * 64 + 4 * lr) = o;
  }
}

extern "C" void kernel_launch(void* const* d_in, const int* in_sizes, int n_in,
                              void* d_out, int out_size, void* d_ws, size_t ws_size,
                              hipStream_t stream) {
  const float* x = (const float*)d_in[0];
  const int* eidx = (const int*)d_in[1];  // int32 per harness conversion
  const float* W = (const float*)d_in[2];
  const float* att = (const float*)d_in[3];
  const float* bias = (const float*)d_in[4];
  float* out = (float*)d_out;

  const int N = in_sizes[0] / 128;
  const int E = in_sizes[1] / 2;
  const int NBKT = (N + 511) >> 9;
  int Cedge = (E + NBKT - 1) / NBKT;
  Cedge = Cedge + Cedge / 8 + 64;  // ~12.5% slack (12+ sigma for random rows)
  Cedge = (Cedge + 15) & ~15;
  if (Cedge > STAGE_CAP) Cedge = STAGE_CAP;
  const int Ctot = Cedge + 512;  // + self-loop slots

  unsigned short* hb = (unsigned short*)d_ws;          // N*64*2 = 12.8 MB
  int* bucket_fill = (int*)(hb + (size_t)N * 64);      // NBKT_MAX ints
  int2* rowinfo = (int2*)(bucket_fill + NBKT_MAX);     // N int2
  unsigned* bucket_arr = (unsigned*)(rowinfo + N);     // NBKT*Ctot u32 (~7.6 MB)

  hipMemsetAsync(bucket_fill, 0, NBKT_MAX * sizeof(int), stream);

  gemm_mfma<<<(N + 255) / 256, 256, 0, stream>>>(x, W, hb, N);
  bucket_pass<<<(E + TILE - 1) / TILE, 256, 0, stream>>>(eidx, eidx + E, bucket_fill,
                                                         bucket_arr, E, Cedge, Ctot, NBKT);
  csr_pass<<<NBKT, 256, 0, stream>>>(bucket_arr, bucket_fill, rowinfo, Cedge, Ctot, N);
  node_pass<<<(N * 64 + 255) / 256, 256, 0, stream>>>(hb, rowinfo, bucket_arr, att, bias,
                                                      out, N);
}